// Round 4
// baseline (789.849 us; speedup 1.0000x reference)
//
#include <hip/hip_runtime.h>

#define NROWS   262144
#define HIDDEN  512
#define NGATES  64
#define NGRAPHS 1024
#define MAXR    512   // max rows/graph handled in-LDS; true max ~310 (mean 256, sd ~16)

typedef __attribute__((ext_vector_type(8))) short short8;
typedef __attribute__((ext_vector_type(4))) float floatx4;

__device__ __forceinline__ unsigned short f2bf(float f) {
    unsigned int u = __float_as_uint(f);
    unsigned int r = (u + 0x7fffu + ((u >> 16) & 1u)) >> 16;
    return (unsigned short)r;
}
__device__ __forceinline__ float bf2f(unsigned short u) {
    return __uint_as_float((unsigned int)u << 16);
}

// K0 (merged setup): blocks 0-15 relayout W -> MFMA B-fragment bf16 (4 tiles each);
// blocks 16-20 compute segment boundaries via binary search (batch sorted).
__global__ void k_setup(const float* __restrict__ W, const int* __restrict__ batch,
                        unsigned short* __restrict__ wf, int* __restrict__ segstart) {
    if (blockIdx.x < 16) {
        int tile = blockIdx.x * 4 + (threadIdx.x >> 6);  // 0..63 = kstep*4 + nt
        int lane = threadIdx.x & 63;
        int kstep = tile >> 2, nt = tile & 3;
        int kbase = kstep * 32 + (lane >> 4) * 8;
        int col   = nt * 16 + (lane & 15);
        unsigned short* dst = wf + ((size_t)tile * 64 + lane) * 8;
#pragma unroll
        for (int j = 0; j < 8; ++j)
            dst[j] = f2bf(W[(size_t)(kbase + j) * NGATES + col]);
    } else {
        int g = (blockIdx.x - 16) * 256 + threadIdx.x;
        if (g > NGRAPHS) return;
        if (g == NGRAPHS) { segstart[g] = NROWS; return; }
        int lo = 0, hi = NROWS;
        while (lo < hi) { int mid = (lo + hi) >> 1; if (batch[mid] < g) lo = mid + 1; else hi = mid; }
        segstart[g] = lo;
    }
}

// K1: one block per graph, 512 threads (8 waves), 2 blocks/CU co-resident so one
// block's HBM-bound phase A overlaps the other's L3-bound phase B.
// Phase A: gate = x@W via bf16 MFMA, e=exp(gate) bf16 in LDS, per-gate sums in LDS.
// Phase B1: per-row mean weight w_i (wave shuffle-reduce over 64 gates).
// Phase B2: out[g] = sum_i w_i * x_i — x slab re-read (512 KB/block, L3-hot).
__global__ __launch_bounds__(512, 4) void k_main(const float* __restrict__ x,
                                                 const unsigned short* __restrict__ wf,
                                                 const int* __restrict__ segstart,
                                                 float* __restrict__ out) {
    __shared__ unsigned short eL[MAXR * NGATES];  // 64 KB; reused as red[2][512] in B2
    __shared__ float wl[MAXR];                    // 2 KB
    __shared__ float sums[NGATES];
    __shared__ float rinv[NGATES];

    const int g = blockIdx.x;
    const int t = threadIdx.x;
    const int lane = t & 63, wv = t >> 6;          // wv in 0..7
    const int m = lane & 15, q = lane >> 4;
    const int s = segstart[g], e = segstart[g + 1];
    const int rows = min(e - s, MAXR);             // defensive clamp (never hit here)
    const int tiles = (rows + 15) >> 4;

    if (t < NGATES) sums[t] = 0.f;
    __syncthreads();

    const short8* wfv = (const short8*)wf;
    float vs0 = 0.f, vs1 = 0.f, vs2 = 0.f, vs3 = 0.f;

    // ---- Phase A ----
    for (int tile = wv; tile < tiles; tile += 8) {
        const int garow = s + tile * 16 + m;                 // this lane's A row
        const float* xrow = x + (size_t)min(garow, NROWS - 1) * HIDDEN + q * 8;

        floatx4 acc0 = {0.f,0.f,0.f,0.f}, acc1 = {0.f,0.f,0.f,0.f};
        floatx4 acc2 = {0.f,0.f,0.f,0.f}, acc3 = {0.f,0.f,0.f,0.f};
#pragma unroll 4
        for (int ks = 0; ks < 16; ++ks) {
            float4 a0 = *(const float4*)(xrow + ks * 32);
            float4 a1 = *(const float4*)(xrow + ks * 32 + 4);
            short8 af;
            af[0] = (short)f2bf(a0.x); af[1] = (short)f2bf(a0.y);
            af[2] = (short)f2bf(a0.z); af[3] = (short)f2bf(a0.w);
            af[4] = (short)f2bf(a1.x); af[5] = (short)f2bf(a1.y);
            af[6] = (short)f2bf(a1.z); af[7] = (short)f2bf(a1.w);
            short8 b0 = wfv[(ks * 4 + 0) * 64 + lane];
            short8 b1 = wfv[(ks * 4 + 1) * 64 + lane];
            short8 b2 = wfv[(ks * 4 + 2) * 64 + lane];
            short8 b3 = wfv[(ks * 4 + 3) * 64 + lane];
            acc0 = __builtin_amdgcn_mfma_f32_16x16x32_bf16(af, b0, acc0, 0, 0, 0);
            acc1 = __builtin_amdgcn_mfma_f32_16x16x32_bf16(af, b1, acc1, 0, 0, 0);
            acc2 = __builtin_amdgcn_mfma_f32_16x16x32_bf16(af, b2, acc2, 0, 0, 0);
            acc3 = __builtin_amdgcn_mfma_f32_16x16x32_bf16(af, b3, acc3, 0, 0, 0);
        }

        // D layout: col = lane&15 (gate), row = q*4 + reg (local row in tile)
        const int rl0 = tile * 16 + q * 4;
#pragma unroll
        for (int r = 0; r < 4; ++r) {
            const int rloc = rl0 + r;
            const bool valid = rloc < rows;
            const float e0 = valid ? __expf(acc0[r]) : 0.f;
            const float e1 = valid ? __expf(acc1[r]) : 0.f;
            const float e2 = valid ? __expf(acc2[r]) : 0.f;
            const float e3 = valid ? __expf(acc3[r]) : 0.f;
            if (valid) {
                unsigned short* eb = eL + rloc * NGATES + m;
                eb[ 0] = f2bf(e0); eb[16] = f2bf(e1);
                eb[32] = f2bf(e2); eb[48] = f2bf(e3);
            }
            vs0 += e0; vs1 += e1; vs2 += e2; vs3 += e3;
        }
    }
    // fold the 4 q-groups, then one LDS atomic per gate per wave
    vs0 += __shfl_xor(vs0, 16, 64); vs0 += __shfl_xor(vs0, 32, 64);
    vs1 += __shfl_xor(vs1, 16, 64); vs1 += __shfl_xor(vs1, 32, 64);
    vs2 += __shfl_xor(vs2, 16, 64); vs2 += __shfl_xor(vs2, 32, 64);
    vs3 += __shfl_xor(vs3, 16, 64); vs3 += __shfl_xor(vs3, 32, 64);
    if (q == 0) {
        atomicAdd(&sums[m],      vs0); atomicAdd(&sums[m + 16], vs1);
        atomicAdd(&sums[m + 32], vs2); atomicAdd(&sums[m + 48], vs3);
    }
    __syncthreads();
    if (t < NGATES) rinv[t] = 1.0f / (sums[t] + 1e-16f);
    __syncthreads();

    // ---- Phase B1: per-row weights (lane = gate) ----
    const float rk = rinv[lane];
    const int nrq = (rows + 3) >> 2;
    for (int i4 = wv; i4 < nrq; i4 += 8) {
        const int rb = i4 * 4;
        float v0 = bf2f(eL[(rb + 0) * NGATES + lane]) * rk;
        float v1 = bf2f(eL[(rb + 1) * NGATES + lane]) * rk;
        float v2 = bf2f(eL[(rb + 2) * NGATES + lane]) * rk;
        float v3 = bf2f(eL[(rb + 3) * NGATES + lane]) * rk;
#pragma unroll
        for (int off = 1; off < 64; off <<= 1) {
            v0 += __shfl_xor(v0, off, 64);
            v1 += __shfl_xor(v1, off, 64);
            v2 += __shfl_xor(v2, off, 64);
            v3 += __shfl_xor(v3, off, 64);
        }
        if (lane == 0) {
            wl[rb + 0] = v0 * (1.0f / 64.0f); wl[rb + 1] = v1 * (1.0f / 64.0f);
            wl[rb + 2] = v2 * (1.0f / 64.0f); wl[rb + 3] = v3 * (1.0f / 64.0f);
        }
    }
    __syncthreads();   // wl visible; eL reads done -> safe to reuse as red

    // ---- Phase B2: weighted pooling, x slab re-read (L3-hot) ----
    const int h2 = (t & 255) * 2;
    const int p = t >> 8;   // 0..1 row-interleave group
    float ax = 0.f, ay = 0.f;
#pragma unroll 4
    for (int i = p; i < rows; i += 2) {
        const float w = wl[i];
        const float2 xv = *(const float2*)(x + (size_t)(s + i) * HIDDEN + h2);
        ax = fmaf(w, xv.x, ax);
        ay = fmaf(w, xv.y, ay);
    }
    float* red = (float*)eL;
    red[(p * 256 + (t & 255)) * 2 + 0] = ax;
    red[(p * 256 + (t & 255)) * 2 + 1] = ay;
    __syncthreads();
    if (p == 0) {
        const int c = (t & 255) * 2;
        float2 o;
        o.x = red[c]     + red[512 + c];
        o.y = red[c + 1] + red[512 + c + 1];
        *(float2*)(out + (size_t)g * HIDDEN + h2) = o;
    }
}

extern "C" void kernel_launch(void* const* d_in, const int* in_sizes, int n_in,
                              void* d_out, int out_size, void* d_ws, size_t ws_size,
                              hipStream_t stream) {
    const float* x     = (const float*)d_in[0];
    const int*   batch = (const int*)d_in[1];
    const float* W     = (const float*)d_in[2];
    float* out = (float*)d_out;

    // ws layout: [0,64K) W frags bf16 | [64K,72K) segstart
    unsigned short* wfrag = (unsigned short*)d_ws;
    int* segstart = (int*)((char*)d_ws + (64 << 10));

    hipLaunchKernelGGL(k_setup, dim3(21), dim3(256), 0, stream, W, batch, wfrag, segstart);
    hipLaunchKernelGGL(k_main, dim3(NGRAPHS), dim3(512), 0, stream, x, wfrag, segstart, out);
}